// Round 5
// baseline (670.979 us; speedup 1.0000x reference)
//
#include <hip/hip_runtime.h>

// Problem constants (B,T,D,H,KVH fixed by the reference)
#define NB 2
#define NT 2048
#define ND 2048
#define NH 16
#define NKVH 4
#define NHD 128
#define NHALF 64
#define NREP (NH / NKVH)

typedef __bf16 bf16x8 __attribute__((ext_vector_type(8)));
typedef unsigned short u16x8 __attribute__((ext_vector_type(8)));
typedef float f32x4 __attribute__((ext_vector_type(4)));

__device__ __forceinline__ unsigned short f2b(float f) {
  union { float f; unsigned int u; } v; v.f = f;
  unsigned int r = v.u + 0x7FFFu + ((v.u >> 16) & 1u);
  return (unsigned short)(r >> 16);
}
__device__ __forceinline__ float b2f(unsigned short h) {
  union { unsigned int u; float f; } v; v.u = ((unsigned int)h) << 16;
  return v.f;
}

// ---------- weight transpose + convert: in (K,N) f32 row-major -> out (N,K) bf16 ----------
__global__ __launch_bounds__(256) void wtrans(const float* __restrict__ in,
                                              unsigned short* __restrict__ out,
                                              int K, int N) {
  __shared__ float tile[32][33];
  const int k0 = blockIdx.y * 32, n0 = blockIdx.x * 32;
  const int x = threadIdx.x & 31, y8 = threadIdx.x >> 5;
#pragma unroll
  for (int j = 0; j < 4; ++j) {
    const int y = y8 + j * 8;
    tile[y][x] = in[(size_t)(k0 + y) * N + n0 + x];
  }
  __syncthreads();
#pragma unroll
  for (int j = 0; j < 4; ++j) {
    const int y = y8 + j * 8;  // output row (= n index)
    out[(size_t)(n0 + y) * K + k0 + x] = f2b(tile[x][y]);
  }
}

// ---------- staging loaders: 8 contiguous elements -> bf16x8 bits ----------
__device__ __forceinline__ u16x8 load8(const float* p) {
  const float4* p4 = (const float4*)p;
  float4 a = p4[0], b = p4[1];
  u16x8 r;
  r[0] = f2b(a.x); r[1] = f2b(a.y); r[2] = f2b(a.z); r[3] = f2b(a.w);
  r[4] = f2b(b.x); r[5] = f2b(b.y); r[6] = f2b(b.z); r[7] = f2b(b.w);
  return r;
}
__device__ __forceinline__ u16x8 load8(const unsigned short* p) {
  return *(const u16x8*)p;
}

// ---------- MFMA GEMM: C(M,N) f32 = A(M,K) @ Bt(N,K)^T, bf16 compute / f32 accum ----------
// 64x64 tile, BK=32, 4 waves (2x2), each wave 2x2 mfma_f32_16x16x32_bf16.
template <typename TA>
__global__ __launch_bounds__(256) void gemm64(const TA* __restrict__ A,
                                              const unsigned short* __restrict__ Bt,
                                              float* __restrict__ C,
                                              int M, int N, int K) {
  __shared__ unsigned short As[64 * 40];  // +8 pad keeps 16B row alignment
  __shared__ unsigned short Bs[64 * 40];
  const int tid = threadIdx.x;
  const int wave = tid >> 6, lane = tid & 63;
  const int wm = wave >> 1, wn = wave & 1;
  const int quad = lane >> 4, lrow = lane & 15;
  const int m0 = blockIdx.y * 64, n0 = blockIdx.x * 64;
  const int sr = tid >> 2;        // staging row 0..63
  const int sc = (tid & 3) * 8;   // staging col {0,8,16,24}

  f32x4 acc[2][2] = {};

  for (int k0 = 0; k0 < K; k0 += 32) {
    u16x8 av = load8(A + (size_t)(m0 + sr) * K + k0 + sc);
    u16x8 bv = load8(Bt + (size_t)(n0 + sr) * K + k0 + sc);
    *(u16x8*)(&As[sr * 40 + sc]) = av;
    *(u16x8*)(&Bs[sr * 40 + sc]) = bv;
    __syncthreads();
#pragma unroll
    for (int sm = 0; sm < 2; ++sm) {
      bf16x8 af = *(const bf16x8*)&As[(wm * 32 + sm * 16 + lrow) * 40 + quad * 8];
#pragma unroll
      for (int sn = 0; sn < 2; ++sn) {
        bf16x8 bfr = *(const bf16x8*)&Bs[(wn * 32 + sn * 16 + lrow) * 40 + quad * 8];
        acc[sm][sn] = __builtin_amdgcn_mfma_f32_16x16x32_bf16(af, bfr, acc[sm][sn], 0, 0, 0);
      }
    }
    __syncthreads();
  }

#pragma unroll
  for (int sm = 0; sm < 2; ++sm)
#pragma unroll
    for (int sn = 0; sn < 2; ++sn) {
      const int row = m0 + wm * 32 + sm * 16 + quad * 4;
      const int col = n0 + wn * 32 + sn * 16 + lrow;
#pragma unroll
      for (int r = 0; r < 4; ++r)
        C[(size_t)(row + r) * N + col] = acc[sm][sn][r];
    }
}

// ---------- fused zc-RMSNorm + RoPE; (B,T,nh,HD) f32 -> (B,nh,T,HD) bf16 ----------
// One wave per (b,t,h) row. Lane l holds dims l and l+64 == the RoPE pair.
// outscale folds the attention 1/sqrt(HD) into Q.
__global__ __launch_bounds__(256) void rmsnorm_rope(const float* __restrict__ in,
                                                    unsigned short* __restrict__ out,
                                                    const float* __restrict__ scale,
                                                    const float* __restrict__ cosp,
                                                    const float* __restrict__ sinp,
                                                    int nh, float outscale) {
  const int wid = blockIdx.x * 4 + (threadIdx.x >> 6);
  const int lane = threadIdx.x & 63;
  const int h = wid % nh;
  const int t = (wid / nh) % NT;
  const int b = wid / (nh * NT);
  const float* x = in + (size_t)wid * NHD;
  float x1 = x[lane], x2 = x[lane + NHALF];
  float ss = x1 * x1 + x2 * x2;
#pragma unroll
  for (int m = 1; m < 64; m <<= 1) ss += __shfl_xor(ss, m, 64);
  const float inv = 1.0f / sqrtf(ss * (1.0f / NHD) + 1e-6f);
  const float n1 = (1.0f + scale[lane]) * x1 * inv;
  const float n2 = (1.0f + scale[lane + NHALF]) * x2 * inv;
  const float c = cosp[t * NHALF + lane], s = sinp[t * NHALF + lane];
  const size_t ob = (((size_t)b * nh + h) * NT + t) * NHD;
  out[ob + lane] = f2b((n1 * c - n2 * s) * outscale);
  out[ob + lane + NHALF] = f2b((n2 * c + n1 * s) * outscale);
}

// ---------- V transpose: (B,T,KVH,HD) f32 -> (B,KVH,HD,T) bf16 (dim-major for PV B-frags) ----------
__global__ __launch_bounds__(256) void vtrans(const float* __restrict__ in,
                                              unsigned short* __restrict__ out) {
  __shared__ float tile[32][33];
  const int bg = blockIdx.z;  // b*NKVH + g
  const int b = bg >> 2, g = bg & 3;
  const int t0 = blockIdx.x * 32, d0 = blockIdx.y * 32;
  const int x = threadIdx.x & 31, y8 = threadIdx.x >> 5;
#pragma unroll
  for (int j = 0; j < 4; ++j) {
    const int y = y8 + j * 8;  // t offset
    tile[y][x] = in[((size_t)(b * NT + t0 + y) * NKVH + g) * NHD + d0 + x];
  }
  __syncthreads();
#pragma unroll
  for (int j = 0; j < 4; ++j) {
    const int y = y8 + j * 8;  // d offset
    out[((size_t)bg * NHD + d0 + y) * NT + t0 + x] = f2b(tile[x][y]);
  }
}

// ---------- MFMA causal flash attention ----------
// grid (B*H, 16). Block = 128 q-rows (4 waves x 32 rows), K-tiles of 64 keys.
// QK^T: A=Q frags (regs), B=K rows (LDS, d-contiguous). Softmax in C-layout regs.
// P -> LDS (bf16) -> A-frags. PV: B=V^T rows (LDS, key-contiguous).
// 1/sqrt(HD) is pre-folded into Qh.
__global__ __launch_bounds__(256, 2) void attn_mfma(const unsigned short* __restrict__ Qh,
                                                    const unsigned short* __restrict__ Kh,
                                                    const unsigned short* __restrict__ Vtg,
                                                    unsigned short* __restrict__ O) {
  __shared__ unsigned short Kt[64 * 136];   // [key][d], stride 136 (272B, 16B-aligned)
  __shared__ unsigned short Vt[128 * 72];   // [d][key], stride 72 (144B)
  __shared__ unsigned short Pt[128 * 72];   // [qrow][key], wave-private 32-row slabs
  const int bh = blockIdx.x;
  const int b = bh / NH, h = bh % NH, g = h / NREP;
  const int yy = blockIdx.y;
  const int qt = (yy < 8) ? yy : 23 - yy;   // pair long+short across CU round-robin
  const int tid = threadIdx.x;
  const int w = tid >> 6, lane = tid & 63;
  const int quad = lane >> 4, c = lane & 15;

  // Q A-fragments: rows qt*128 + w*32 + sm*16 + c, k = ch*32 + quad*8 + j
  bf16x8 qf[2][4];
  const size_t qbase = (size_t)(b * NH + h) * NT;
#pragma unroll
  for (int sm = 0; sm < 2; ++sm) {
    const unsigned short* qp =
        Qh + (qbase + qt * 128 + w * 32 + sm * 16 + c) * NHD + quad * 8;
#pragma unroll
    for (int ch = 0; ch < 4; ++ch) qf[sm][ch] = *(const bf16x8*)(qp + ch * 32);
  }

  f32x4 acc_o[2][8] = {};           // [sm][n2]: row quad*4+r, dim n2*16+c
  float mrow[2][4], lrow[2][4];     // per-lane row state (rows quad*4+r)
#pragma unroll
  for (int sm = 0; sm < 2; ++sm)
#pragma unroll
    for (int r = 0; r < 4; ++r) { mrow[sm][r] = -1e30f; lrow[sm][r] = 0.0f; }

  const size_t kbase = (size_t)(b * NKVH + g) * NT * NHD;  // (key, d) rows
  const size_t vbase = (size_t)(b * NKVH + g) * NHD * NT;  // (d, key) rows
  const int rowb = qt * 128 + w * 32 + quad * 4;           // + sm*16 + r
  const int rowmax_w = qt * 128 + w * 32 + 31;
  const int nkt = 2 * qt + 2;

  for (int kt = 0; kt < nkt; ++kt) {
    const int k0 = kt * 64;
    // stage K (64x128) and V^T (128x64)
#pragma unroll
    for (int j = 0; j < 4; ++j) {
      const int f = j * 256 + tid;
      const int kr = f >> 4, kc_ = (f & 15) * 8;
      *(u16x8*)&Kt[kr * 136 + kc_] =
          *(const u16x8*)&Kh[kbase + (size_t)(k0 + kr) * NHD + kc_];
      const int vd = f >> 3, vc = (f & 7) * 8;
      *(u16x8*)&Vt[vd * 72 + vc] =
          *(const u16x8*)&Vtg[vbase + (size_t)vd * NT + k0 + vc];
    }
    __syncthreads();

    if (k0 <= rowmax_w) {  // wave has at least one unmasked key in this tile
      // ---- S = Q K^T : 16x64 per sm ----
      f32x4 s[2][4] = {};
#pragma unroll
      for (int n = 0; n < 4; ++n)
#pragma unroll
        for (int ch = 0; ch < 4; ++ch) {
          bf16x8 kf = *(const bf16x8*)&Kt[(n * 16 + c) * 136 + ch * 32 + quad * 8];
          s[0][n] = __builtin_amdgcn_mfma_f32_16x16x32_bf16(qf[0][ch], kf, s[0][n], 0, 0, 0);
          s[1][n] = __builtin_amdgcn_mfma_f32_16x16x32_bf16(qf[1][ch], kf, s[1][n], 0, 0, 0);
        }

      // ---- online softmax (C-layout: row quad*4+r, key n*16+c) ----
      const bool need_mask = (kt >= 2 * qt);
#pragma unroll
      for (int sm = 0; sm < 2; ++sm) {
#pragma unroll
        for (int r = 0; r < 4; ++r) {
          float v0 = s[sm][0][r], v1 = s[sm][1][r], v2 = s[sm][2][r], v3 = s[sm][3][r];
          if (need_mask) {
            const int qp_ = rowb + sm * 16 + r;
            if (k0 + c > qp_) v0 = -1e30f;
            if (k0 + 16 + c > qp_) v1 = -1e30f;
            if (k0 + 32 + c > qp_) v2 = -1e30f;
            if (k0 + 48 + c > qp_) v3 = -1e30f;
          }
          float tm = fmaxf(fmaxf(v0, v1), fmaxf(v2, v3));
          tm = fmaxf(tm, __shfl_xor(tm, 1, 64));
          tm = fmaxf(tm, __shfl_xor(tm, 2, 64));
          tm = fmaxf(tm, __shfl_xor(tm, 4, 64));
          tm = fmaxf(tm, __shfl_xor(tm, 8, 64));
          const float nm = fmaxf(mrow[sm][r], tm);
          const float alpha = __expf(mrow[sm][r] - nm);
          mrow[sm][r] = nm;
          const float p0 = __expf(v0 - nm), p1 = __expf(v1 - nm);
          const float p2 = __expf(v2 - nm), p3 = __expf(v3 - nm);
          float ps = p0 + p1 + p2 + p3;
          ps += __shfl_xor(ps, 1, 64);
          ps += __shfl_xor(ps, 2, 64);
          ps += __shfl_xor(ps, 4, 64);
          ps += __shfl_xor(ps, 8, 64);
          lrow[sm][r] = lrow[sm][r] * alpha + ps;
#pragma unroll
          for (int n2 = 0; n2 < 8; ++n2) acc_o[sm][n2][r] *= alpha;
          const int prow = w * 32 + sm * 16 + quad * 4 + r;
          Pt[prow * 72 + c] = f2b(p0);
          Pt[prow * 72 + 16 + c] = f2b(p1);
          Pt[prow * 72 + 32 + c] = f2b(p2);
          Pt[prow * 72 + 48 + c] = f2b(p3);
        }
      }

      // ---- O += P V : P A-frags from LDS, V^T B-frags ----
#pragma unroll
      for (int kc2 = 0; kc2 < 2; ++kc2) {
        bf16x8 pf0 = *(const bf16x8*)&Pt[(w * 32 + c) * 72 + kc2 * 32 + quad * 8];
        bf16x8 pf1 = *(const bf16x8*)&Pt[(w * 32 + 16 + c) * 72 + kc2 * 32 + quad * 8];
#pragma unroll
        for (int n2 = 0; n2 < 8; ++n2) {
          bf16x8 vf = *(const bf16x8*)&Vt[(n2 * 16 + c) * 72 + kc2 * 32 + quad * 8];
          acc_o[0][n2] = __builtin_amdgcn_mfma_f32_16x16x32_bf16(pf0, vf, acc_o[0][n2], 0, 0, 0);
          acc_o[1][n2] = __builtin_amdgcn_mfma_f32_16x16x32_bf16(pf1, vf, acc_o[1][n2], 0, 0, 0);
        }
      }
    }
    __syncthreads();
  }

  // epilogue: O[(b,t,h,:)] = acc / l   (Ob layout (B,T,H,HD) == (B*T, D))
#pragma unroll
  for (int sm = 0; sm < 2; ++sm) {
    const int qrow = qt * 128 + w * 32 + sm * 16 + quad * 4;
#pragma unroll
    for (int r = 0; r < 4; ++r) {
      const float invl = 1.0f / lrow[sm][r];
      unsigned short* op = O + ((size_t)(b * NT + qrow + r) * NH + h) * NHD + c;
#pragma unroll
      for (int n2 = 0; n2 < 8; ++n2) op[n2 * 16] = f2b(acc_o[sm][n2][r] * invl);
    }
  }
}

extern "C" void kernel_launch(void* const* d_in, const int* in_sizes, int n_in,
                              void* d_out, int out_size, void* d_ws, size_t ws_size,
                              hipStream_t stream) {
  (void)in_sizes; (void)n_in; (void)out_size; (void)ws_size;
  const float* q_input  = (const float*)d_in[0];
  const float* kv_input = (const float*)d_in[1];
  // d_in[2] = mask (static causal tril) — applied analytically
  const float* cosp = (const float*)d_in[3];
  const float* sinp = (const float*)d_in[4];
  const float* Wq = (const float*)d_in[5];
  const float* Wk = (const float*)d_in[6];
  const float* Wv = (const float*)d_in[7];
  const float* q_scale = (const float*)d_in[8];
  const float* k_scale = (const float*)d_in[9];
  const float* Wo = (const float*)d_in[10];
  float* out = (float*)d_out;

  // workspace carve (~113 MB total)
  char* p = (char*)d_ws;
  float* Q  = (float*)p; p += (size_t)NB * NT * ND * 4;
  float* Kp = (float*)p; p += (size_t)NB * NT * NKVH * NHD * 4;
  float* Vp = (float*)p; p += (size_t)NB * NT * NKVH * NHD * 4;
  unsigned short* Qh  = (unsigned short*)p; p += (size_t)NB * NT * ND * 2;
  unsigned short* Kh  = (unsigned short*)p; p += (size_t)NB * NT * NKVH * NHD * 2;
  unsigned short* Vtg = (unsigned short*)p; p += (size_t)NB * NT * NKVH * NHD * 2;
  unsigned short* Ob  = (unsigned short*)p; p += (size_t)NB * NT * ND * 2;
  unsigned short* Wqt = (unsigned short*)p; p += (size_t)ND * ND * 2;
  unsigned short* Wkt = (unsigned short*)p; p += (size_t)ND * NKVH * NHD * 2;
  unsigned short* Wvt = (unsigned short*)p; p += (size_t)ND * NKVH * NHD * 2;
  unsigned short* Wot = (unsigned short*)p; p += (size_t)ND * ND * 2;

  const dim3 blk(256);
  const int M = NB * NT;        // 4096
  const int NKV = NKVH * NHD;   // 512

  wtrans<<<dim3(ND / 32, ND / 32), blk, 0, stream>>>(Wq, Wqt, ND, ND);
  wtrans<<<dim3(NKV / 32, ND / 32), blk, 0, stream>>>(Wk, Wkt, ND, NKV);
  wtrans<<<dim3(NKV / 32, ND / 32), blk, 0, stream>>>(Wv, Wvt, ND, NKV);
  wtrans<<<dim3(ND / 32, ND / 32), blk, 0, stream>>>(Wo, Wot, ND, ND);

  gemm64<float><<<dim3(ND / 64, M / 64), blk, 0, stream>>>(q_input, Wqt, Q, M, ND, ND);
  gemm64<float><<<dim3(NKV / 64, M / 64), blk, 0, stream>>>(kv_input, Wkt, Kp, M, NKV, ND);
  gemm64<float><<<dim3(NKV / 64, M / 64), blk, 0, stream>>>(kv_input, Wvt, Vp, M, NKV, ND);

  // fixups: rmsnorm + rope + relayout; Q gets 1/sqrt(HD) folded in
  rmsnorm_rope<<<dim3(NB * NT * NH / 4), blk, 0, stream>>>(Q, Qh, q_scale, cosp, sinp, NH,
                                                           0.08838834764831845f);
  rmsnorm_rope<<<dim3(NB * NT * NKVH / 4), blk, 0, stream>>>(Kp, Kh, k_scale, cosp, sinp, NKVH,
                                                             1.0f);
  vtrans<<<dim3(NT / 32, NHD / 32, NB * NKVH), blk, 0, stream>>>(Vp, Vtg);

  // MFMA causal GQA flash attention -> Ob (B,T,H,HD)
  attn_mfma<<<dim3(NB * NH, 16), blk, 0, stream>>>(Qh, Kh, Vtg, Ob);

  // output projection -> d_out (f32)
  gemm64<unsigned short><<<dim3(ND / 64, M / 64), blk, 0, stream>>>(Ob, Wot, out, M, ND, ND);
}

// Round 6
// 428.679 us; speedup vs baseline: 1.5652x; 1.5652x over previous
//
#include <hip/hip_runtime.h>

// Problem constants (B,T,D,H,KVH fixed by the reference)
#define NB 2
#define NT 2048
#define ND 2048
#define NH 16
#define NKVH 4
#define NHD 128
#define NHALF 64
#define NREP (NH / NKVH)
#define MFIX 12.0f  // fixed softmax max: |score| <= sqrt(128) ~= 11.32 after zc-rmsnorm

typedef __bf16 bf16x8 __attribute__((ext_vector_type(8)));
typedef unsigned short u16x8 __attribute__((ext_vector_type(8)));
typedef float f32x4 __attribute__((ext_vector_type(4)));

__device__ __forceinline__ unsigned short f2b(float f) {
  union { float f; unsigned int u; } v; v.f = f;
  unsigned int r = v.u + 0x7FFFu + ((v.u >> 16) & 1u);
  return (unsigned short)(r >> 16);
}
__device__ __forceinline__ float b2f(unsigned short h) {
  union { unsigned int u; float f; } v; v.u = ((unsigned int)h) << 16;
  return v.f;
}

// ---------- f32 -> bf16 elementwise (8/thread) ----------
__global__ __launch_bounds__(256) void f2bf(const float* __restrict__ in,
                                            unsigned short* __restrict__ out) {
  const size_t i = (size_t)(blockIdx.x * 256 + threadIdx.x) * 8;
  float4 a = *(const float4*)(in + i);
  float4 b = *(const float4*)(in + i + 4);
  u16x8 r;
  r[0] = f2b(a.x); r[1] = f2b(a.y); r[2] = f2b(a.z); r[3] = f2b(a.w);
  r[4] = f2b(b.x); r[5] = f2b(b.y); r[6] = f2b(b.z); r[7] = f2b(b.w);
  *(u16x8*)(out + i) = r;
}

// ---------- weight transpose + convert: in (K,N) f32 -> out (N,K) bf16 ----------
__global__ __launch_bounds__(256) void wtrans(const float* __restrict__ in,
                                              unsigned short* __restrict__ out,
                                              int K, int N) {
  __shared__ float tile[32][33];
  const int k0 = blockIdx.y * 32, n0 = blockIdx.x * 32;
  const int x = threadIdx.x & 31, y8 = threadIdx.x >> 5;
#pragma unroll
  for (int j = 0; j < 4; ++j) {
    const int y = y8 + j * 8;
    tile[y][x] = in[(size_t)(k0 + y) * N + n0 + x];
  }
  __syncthreads();
#pragma unroll
  for (int j = 0; j < 4; ++j) {
    const int y = y8 + j * 8;
    out[(size_t)(n0 + y) * K + k0 + x] = f2b(tile[x][y]);
  }
}

// ---------- MFMA GEMM: C(M,N) f32 = A(M,K)bf16 @ Bt(N,K)bf16^T ----------
// 128x128 tile, BK=32, 4 waves (2x2 of 64x64), each 4x4 mfma_f32_16x16x32_bf16.
// Pure-copy staging (no convert), register prefetch of next K-step.
__global__ __launch_bounds__(256) void gemm128(const unsigned short* __restrict__ A,
                                               const unsigned short* __restrict__ Bt,
                                               float* __restrict__ C,
                                               int M, int N, int K) {
  __shared__ unsigned short As[128 * 40];  // stride 40: 2-way-only bank aliasing (free)
  __shared__ unsigned short Bs[128 * 40];
  const int tid = threadIdx.x;
  const int wave = tid >> 6, lane = tid & 63;
  const int wm = wave >> 1, wn = wave & 1;
  const int quad = lane >> 4, c = lane & 15;
  const int m0 = blockIdx.y * 128, n0 = blockIdx.x * 128;
  const int sr = tid >> 2;        // 0..63 (rows sr and 64+sr)
  const int sc = (tid & 3) * 8;   // 0,8,16,24

  f32x4 acc[4][4] = {};

  u16x8 a0 = *(const u16x8*)(A + (size_t)(m0 + sr) * K + sc);
  u16x8 a1 = *(const u16x8*)(A + (size_t)(m0 + 64 + sr) * K + sc);
  u16x8 b0 = *(const u16x8*)(Bt + (size_t)(n0 + sr) * K + sc);
  u16x8 b1 = *(const u16x8*)(Bt + (size_t)(n0 + 64 + sr) * K + sc);

  for (int k0 = 0; k0 < K; k0 += 32) {
    *(u16x8*)&As[sr * 40 + sc] = a0;
    *(u16x8*)&As[(64 + sr) * 40 + sc] = a1;
    *(u16x8*)&Bs[sr * 40 + sc] = b0;
    *(u16x8*)&Bs[(64 + sr) * 40 + sc] = b1;
    __syncthreads();
    const int kn = k0 + 32;
    if (kn < K) {  // prefetch next K-step; vmcnt wait lands at next LDS write
      a0 = *(const u16x8*)(A + (size_t)(m0 + sr) * K + kn + sc);
      a1 = *(const u16x8*)(A + (size_t)(m0 + 64 + sr) * K + kn + sc);
      b0 = *(const u16x8*)(Bt + (size_t)(n0 + sr) * K + kn + sc);
      b1 = *(const u16x8*)(Bt + (size_t)(n0 + 64 + sr) * K + kn + sc);
    }
    bf16x8 af[4];
#pragma unroll
    for (int sm = 0; sm < 4; ++sm)
      af[sm] = *(const bf16x8*)&As[(wm * 64 + sm * 16 + c) * 40 + quad * 8];
#pragma unroll
    for (int sn = 0; sn < 4; ++sn) {
      bf16x8 bfr = *(const bf16x8*)&Bs[(wn * 64 + sn * 16 + c) * 40 + quad * 8];
#pragma unroll
      for (int sm = 0; sm < 4; ++sm)
        acc[sm][sn] = __builtin_amdgcn_mfma_f32_16x16x32_bf16(af[sm], bfr, acc[sm][sn], 0, 0, 0);
    }
    __syncthreads();
  }

#pragma unroll
  for (int sm = 0; sm < 4; ++sm)
#pragma unroll
    for (int sn = 0; sn < 4; ++sn) {
      const int row = m0 + wm * 64 + sm * 16 + quad * 4;
      const int col = n0 + wn * 64 + sn * 16 + c;
#pragma unroll
      for (int r = 0; r < 4; ++r)
        C[(size_t)(row + r) * N + col] = acc[sm][sn][r];
    }
}

// ---------- fused zc-RMSNorm + RoPE; rows (b,t,h) -> (B,nh,T,HD) bf16 ----------
// instride = f32 row stride of the (b,t) row; head h at offset h*NHD within it.
__global__ __launch_bounds__(256) void rmsnorm_rope(const float* __restrict__ in,
                                                    unsigned short* __restrict__ out,
                                                    const float* __restrict__ scale,
                                                    const float* __restrict__ cosp,
                                                    const float* __restrict__ sinp,
                                                    int nh, int instride, float outscale) {
  const int wid = blockIdx.x * 4 + (threadIdx.x >> 6);
  const int lane = threadIdx.x & 63;
  const int h = wid % nh;
  const int t = (wid / nh) % NT;
  const int b = wid / (nh * NT);
  const float* x = in + (size_t)(b * NT + t) * instride + h * NHD;
  float x1 = x[lane], x2 = x[lane + NHALF];
  float ss = x1 * x1 + x2 * x2;
#pragma unroll
  for (int m = 1; m < 64; m <<= 1) ss += __shfl_xor(ss, m, 64);
  const float inv = 1.0f / sqrtf(ss * (1.0f / NHD) + 1e-6f);
  const float n1 = (1.0f + scale[lane]) * x1 * inv;
  const float n2 = (1.0f + scale[lane + NHALF]) * x2 * inv;
  const float cc = cosp[t * NHALF + lane], s = sinp[t * NHALF + lane];
  const size_t ob = (((size_t)b * nh + h) * NT + t) * NHD;
  out[ob + lane] = f2b((n1 * cc - n2 * s) * outscale);
  out[ob + lane + NHALF] = f2b((n2 * cc + n1 * s) * outscale);
}

// ---------- V transpose: rows (b,t) f32 (stride instride, group g at g*NHD) -> (B,KVH,HD,T) bf16 ----------
__global__ __launch_bounds__(256) void vtrans(const float* __restrict__ in,
                                              unsigned short* __restrict__ out,
                                              int instride) {
  __shared__ float tile[32][33];
  const int bg = blockIdx.z;  // b*NKVH + g
  const int b = bg >> 2, g = bg & 3;
  const int t0 = blockIdx.x * 32, d0 = blockIdx.y * 32;
  const int x = threadIdx.x & 31, y8 = threadIdx.x >> 5;
#pragma unroll
  for (int j = 0; j < 4; ++j) {
    const int y = y8 + j * 8;  // t offset
    tile[y][x] = in[(size_t)(b * NT + t0 + y) * instride + g * NHD + d0 + x];
  }
  __syncthreads();
#pragma unroll
  for (int j = 0; j < 4; ++j) {
    const int y = y8 + j * 8;  // d offset
    out[((size_t)bg * NHD + d0 + y) * NT + t0 + x] = f2b(tile[x][y]);
  }
}

// ---------- MFMA causal flash attention, 64-row Q-tiles ----------
// grid (B*H, 32). Block = 64 q-rows (4 waves x 16 rows), K-tiles of 64 keys.
// Fixed-max softmax (MFIX): no per-tile reductions, no O-rescale; one l-reduction at end.
// LDS 45056 B -> 3 blocks/CU. 1/sqrt(HD) pre-folded into Qh.
__global__ __launch_bounds__(256, 3) void attn64(const unsigned short* __restrict__ Qh,
                                                 const unsigned short* __restrict__ Kh,
                                                 const unsigned short* __restrict__ Vtg,
                                                 unsigned short* __restrict__ O) {
  __shared__ unsigned short Kt[64 * 136];  // [key][d]
  __shared__ unsigned short Vt[128 * 72];  // [d][key]
  __shared__ unsigned short Pt[64 * 72];   // [qrow][key], wave-private 16-row slabs
  const int bh = blockIdx.x;
  const int b = bh / NH, h = bh % NH, g = h / NREP;
  const int y = blockIdx.y;
  const int a = y & 7, bb = y >> 3;
  // CU-balanced qt map: each a-group gets {a, a+8, 31-a, 23-a} (sum = 62, constant)
  const int qt = (bb == 0) ? a : (bb == 1) ? a + 8 : (bb == 2) ? 31 - a : 23 - a;
  const int tid = threadIdx.x;
  const int w = tid >> 6, lane = tid & 63;
  const int quad = lane >> 4, c = lane & 15;

  // Q A-fragments: rows qt*64 + w*16 + c, k = ch*32 + quad*8 + j
  bf16x8 qf[4];
  {
    const unsigned short* qp =
        Qh + ((size_t)(b * NH + h) * NT + qt * 64 + w * 16 + c) * NHD + quad * 8;
#pragma unroll
    for (int ch = 0; ch < 4; ++ch) qf[ch] = *(const bf16x8*)(qp + ch * 32);
  }

  f32x4 acc_o[8] = {};              // [n2]: row quad*4+r, dim n2*16+c
  float lsum[4] = {0.f, 0.f, 0.f, 0.f};
  const size_t kbase = (size_t)(b * NKVH + g) * NT * NHD;
  const size_t vbase = (size_t)(b * NKVH + g) * NHD * NT;
  const int nkt = qt + 1;

  for (int kt = 0; kt < nkt; ++kt) {
    const int k0 = kt * 64;
#pragma unroll
    for (int j = 0; j < 4; ++j) {
      const int f = j * 256 + tid;
      const int kr = f >> 4, kc_ = (f & 15) * 8;
      *(u16x8*)&Kt[kr * 136 + kc_] =
          *(const u16x8*)&Kh[kbase + (size_t)(k0 + kr) * NHD + kc_];
      const int vd = f >> 3, vc = (f & 7) * 8;
      *(u16x8*)&Vt[vd * 72 + vc] =
          *(const u16x8*)&Vtg[vbase + (size_t)vd * NT + k0 + vc];
    }
    __syncthreads();

    // ---- S = Q K^T (16 x 64) ----
    f32x4 s[4] = {};
#pragma unroll
    for (int n = 0; n < 4; ++n)
#pragma unroll
      for (int ch = 0; ch < 4; ++ch) {
        bf16x8 kf = *(const bf16x8*)&Kt[(n * 16 + c) * 136 + ch * 32 + quad * 8];
        s[n] = __builtin_amdgcn_mfma_f32_16x16x32_bf16(qf[ch], kf, s[n], 0, 0, 0);
      }

    // ---- fixed-max softmax; P -> LDS (bf16) ----
    const bool dmask = (kt == qt);  // only the diagonal tile masks
#pragma unroll
    for (int r = 0; r < 4; ++r) {
      float v0 = s[0][r], v1 = s[1][r], v2 = s[2][r], v3 = s[3][r];
      const int lrow = w * 16 + quad * 4 + r;  // row within block; key offset n*16+c
      if (dmask) {
        if (c > lrow) v0 = -1e30f;
        if (16 + c > lrow) v1 = -1e30f;
        if (32 + c > lrow) v2 = -1e30f;
        if (48 + c > lrow) v3 = -1e30f;
      }
      const float p0 = __expf(v0 - MFIX), p1 = __expf(v1 - MFIX);
      const float p2 = __expf(v2 - MFIX), p3 = __expf(v3 - MFIX);
      lsum[r] += (p0 + p1) + (p2 + p3);
      Pt[lrow * 72 + c] = f2b(p0);
      Pt[lrow * 72 + 16 + c] = f2b(p1);
      Pt[lrow * 72 + 32 + c] = f2b(p2);
      Pt[lrow * 72 + 48 + c] = f2b(p3);
    }

    // ---- O += P V ----
#pragma unroll
    for (int kc2 = 0; kc2 < 2; ++kc2) {
      bf16x8 pf = *(const bf16x8*)&Pt[(w * 16 + c) * 72 + kc2 * 32 + quad * 8];
#pragma unroll
      for (int n2 = 0; n2 < 8; ++n2) {
        bf16x8 vf = *(const bf16x8*)&Vt[(n2 * 16 + c) * 72 + kc2 * 32 + quad * 8];
        acc_o[n2] = __builtin_amdgcn_mfma_f32_16x16x32_bf16(pf, vf, acc_o[n2], 0, 0, 0);
      }
    }
    __syncthreads();
  }

  // one cross-lane l reduction (within 16-lane c-group)
#pragma unroll
  for (int r = 0; r < 4; ++r) {
    float l = lsum[r];
    l += __shfl_xor(l, 1, 64);
    l += __shfl_xor(l, 2, 64);
    l += __shfl_xor(l, 4, 64);
    l += __shfl_xor(l, 8, 64);
    lsum[r] = l;
  }

#pragma unroll
  for (int r = 0; r < 4; ++r) {
    const float invl = 1.0f / lsum[r];
    const int qrow = qt * 64 + w * 16 + quad * 4 + r;
    unsigned short* op = O + ((size_t)(b * NT + qrow) * NH + h) * NHD + c;
#pragma unroll
    for (int n2 = 0; n2 < 8; ++n2) op[n2 * 16] = f2b(acc_o[n2][r] * invl);
  }
}

extern "C" void kernel_launch(void* const* d_in, const int* in_sizes, int n_in,
                              void* d_out, int out_size, void* d_ws, size_t ws_size,
                              hipStream_t stream) {
  (void)in_sizes; (void)n_in; (void)out_size; (void)ws_size;
  const float* q_input  = (const float*)d_in[0];
  const float* kv_input = (const float*)d_in[1];
  // d_in[2] = mask (static causal tril) — applied analytically
  const float* cosp = (const float*)d_in[3];
  const float* sinp = (const float*)d_in[4];
  const float* Wq = (const float*)d_in[5];
  const float* Wk = (const float*)d_in[6];
  const float* Wv = (const float*)d_in[7];
  const float* q_scale = (const float*)d_in[8];
  const float* k_scale = (const float*)d_in[9];
  const float* Wo = (const float*)d_in[10];
  float* out = (float*)d_out;

  // workspace carve (~108 MB) with lifetime-safe aliases
  char* p = (char*)d_ws;
  float* Q32  = (float*)p; p += (size_t)NB * NT * ND * 4;        // 33.5 MB
  float* KVp  = (float*)p; p += (size_t)NB * NT * 1024 * 4;      // 16.8 MB (K cols 0..511, V cols 512..1023)
  unsigned short* Qb16  = (unsigned short*)p; p += (size_t)NB * NT * ND * 2;  // 16.8 MB
  unsigned short* KVb16 = (unsigned short*)p; p += (size_t)NB * NT * ND * 2;  // 16.8 MB
  unsigned short* Kh  = (unsigned short*)p; p += (size_t)NB * NKVH * NT * NHD * 2;  // 4.2 MB
  unsigned short* Vtg = (unsigned short*)p; p += (size_t)NB * NKVH * NT * NHD * 2;  // 4.2 MB
  unsigned short* Wqt  = (unsigned short*)p; p += (size_t)ND * ND * 2;         // 8.4 MB
  unsigned short* WkvT = (unsigned short*)p; p += (size_t)1024 * ND * 2;       // 4.2 MB
  unsigned short* Wot  = (unsigned short*)p; p += (size_t)ND * ND * 2;         // 8.4 MB
  // aliases: Qb16 dead after Q-proj -> reuse as Ob; KVb16 dead after KV-proj -> reuse as Qh
  unsigned short* Ob = Qb16;
  unsigned short* Qh = KVb16;

  const dim3 blk(256);
  const int M = NB * NT;  // 4096

  // activation f32 -> bf16 (one-time)
  f2bf<<<dim3(M * ND / 2048), blk, 0, stream>>>(q_input, Qb16);
  f2bf<<<dim3(M * ND / 2048), blk, 0, stream>>>(kv_input, KVb16);

  // weight transpose+convert; Wk|Wv fused into WkvT (rows 0..511 = K, 512..1023 = V)
  wtrans<<<dim3(ND / 32, ND / 32), blk, 0, stream>>>(Wq, Wqt, ND, ND);
  wtrans<<<dim3(512 / 32, ND / 32), blk, 0, stream>>>(Wk, WkvT, ND, 512);
  wtrans<<<dim3(512 / 32, ND / 32), blk, 0, stream>>>(Wv, WkvT + (size_t)512 * ND, ND, 512);
  wtrans<<<dim3(ND / 32, ND / 32), blk, 0, stream>>>(Wo, Wot, ND, ND);

  // projections (128x128 tiles)
  gemm128<<<dim3(ND / 128, M / 128), blk, 0, stream>>>(Qb16, Wqt, Q32, M, ND, ND);
  gemm128<<<dim3(1024 / 128, M / 128), blk, 0, stream>>>(KVb16, WkvT, KVp, M, 1024, ND);

  // fixups: rmsnorm + rope + relayout; Q gets 1/sqrt(HD) folded in
  rmsnorm_rope<<<dim3(NB * NT * NH / 4), blk, 0, stream>>>(Q32, Qh, q_scale, cosp, sinp,
                                                           NH, ND, 0.08838834764831845f);
  rmsnorm_rope<<<dim3(NB * NT * NKVH / 4), blk, 0, stream>>>(KVp, Kh, k_scale, cosp, sinp,
                                                             NKVH, 1024, 1.0f);
  vtrans<<<dim3(NT / 32, NHD / 32, NB * NKVH), blk, 0, stream>>>(KVp + 512, Vtg, 1024);

  // MFMA causal GQA flash attention -> Ob (B,T,H,HD)
  attn64<<<dim3(NB * NH, 32), blk, 0, stream>>>(Qh, Kh, Vtg, Ob);

  // output projection -> d_out (f32)
  gemm128<<<dim3(ND / 128, M / 128), blk, 0, stream>>>(Ob, Wot, out, M, ND, ND);
}